// Round 1
// baseline (478.861 us; speedup 1.0000x reference)
//
#include <hip/hip_runtime.h>
#include <math.h>

#define DD 256
#define GG 2048

__device__ __forceinline__ unsigned fkey(float f) {
  unsigned u = __float_as_uint(f);
  return (u & 0x80000000u) ? ~u : (u | 0x80000000u);
}
__device__ __forceinline__ float funkey(unsigned k) {
  unsigned u = (k & 0x80000000u) ? (k & 0x7fffffffu) : ~k;
  return __uint_as_float(u);
}

__global__ void k_zero(float* __restrict__ p, int n) {
  int i = blockIdx.x * blockDim.x + threadIdx.x;
  if (i < n) p[i] = 0.f;
}

// ---------------- pass 1: h_sum, counts, h_max, attn softmax-pool ----------------
__global__ __launch_bounds__(256) void k_pass1(
    const float* __restrict__ x, const int* __restrict__ batch,
    const float* __restrict__ w_attn,
    float* __restrict__ hsum, unsigned* __restrict__ hmaxk,
    float* __restrict__ counts, float* __restrict__ z1,
    float* __restrict__ natt, int N, int rowsPerWave)
{
  const int lane = threadIdx.x & 63;
  const int wave = blockIdx.x * (blockDim.x >> 6) + (threadIdx.x >> 6);
  long r0 = (long)wave * rowsPerWave;
  if (r0 >= N) return;
  long r1 = r0 + rowsPerWave; if (r1 > N) r1 = N;
  const int d0 = lane * 4;
  const float4 wa = *(const float4*)(w_attn + d0);

  float sx=0,sy=0,sz=0,sw=0;          // h_sum
  float ax=0,ay=0,az=0,aw=0;          // attn numerator
  const float NEG = -3.402823466e38f;
  float mx=NEG,my=NEG,mz=NEG,mw=NEG;  // h_max
  float cnt=0.f, ez=0.f;
  int cur = batch[r0];

  for (long r = r0; r < r1; ++r) {
    int b = batch[r];
    if (b != cur) {
      float* ps = hsum + (size_t)cur*DD + d0;
      atomicAdd(ps+0,sx); atomicAdd(ps+1,sy); atomicAdd(ps+2,sz); atomicAdd(ps+3,sw);
      unsigned* pm = hmaxk + (size_t)cur*DD + d0;
      atomicMax(pm+0,fkey(mx)); atomicMax(pm+1,fkey(my));
      atomicMax(pm+2,fkey(mz)); atomicMax(pm+3,fkey(mw));
      float* pa = natt + (size_t)cur*DD + d0;
      atomicAdd(pa+0,ax); atomicAdd(pa+1,ay); atomicAdd(pa+2,az); atomicAdd(pa+3,aw);
      if (lane == 0) { atomicAdd(counts+cur,cnt); atomicAdd(z1+cur,ez); }
      sx=sy=sz=sw=0; ax=ay=az=aw=0; mx=my=mz=mw=NEG; cnt=0; ez=0;
      cur = b;
    }
    const float4 v = *(const float4*)(x + (size_t)r*DD + d0);
    float p = v.x*wa.x + v.y*wa.y + v.z*wa.z + v.w*wa.w;
    #pragma unroll
    for (int o = 32; o; o >>= 1) p += __shfl_xor(p, o);
    float e = expf(p);   // unstabilized: softmax shift-invariance makes this exact
    sx += v.x; sy += v.y; sz += v.z; sw += v.w;
    mx = fmaxf(mx,v.x); my = fmaxf(my,v.y); mz = fmaxf(mz,v.z); mw = fmaxf(mw,v.w);
    ax += v.x*e; ay += v.y*e; az += v.z*e; aw += v.w*e;
    cnt += 1.f; ez += e;
  }
  {
    float* ps = hsum + (size_t)cur*DD + d0;
    atomicAdd(ps+0,sx); atomicAdd(ps+1,sy); atomicAdd(ps+2,sz); atomicAdd(ps+3,sw);
    unsigned* pm = hmaxk + (size_t)cur*DD + d0;
    atomicMax(pm+0,fkey(mx)); atomicMax(pm+1,fkey(my));
    atomicMax(pm+2,fkey(mz)); atomicMax(pm+3,fkey(mw));
    float* pa = natt + (size_t)cur*DD + d0;
    atomicAdd(pa+0,ax); atomicAdd(pa+1,ay); atomicAdd(pa+2,az); atomicAdd(pa+3,aw);
    if (lane == 0) { atomicAdd(counts+cur,cnt); atomicAdd(z1+cur,ez); }
  }
}

// ---------------- pass 2: s2s softmax-pool via qs = Wk q / 16 ----------------
__global__ __launch_bounds__(256) void k_pass2(
    const float* __restrict__ x, const int* __restrict__ batch,
    const float* __restrict__ qs,
    float* __restrict__ z2, float* __restrict__ ns2s, int N, int rowsPerWave)
{
  const int lane = threadIdx.x & 63;
  const int wave = blockIdx.x * (blockDim.x >> 6) + (threadIdx.x >> 6);
  long r0 = (long)wave * rowsPerWave;
  if (r0 >= N) return;
  long r1 = r0 + rowsPerWave; if (r1 > N) r1 = N;
  const int d0 = lane * 4;

  int cur = batch[r0];
  float4 qv = *(const float4*)(qs + (size_t)cur*DD + d0);
  float sx=0,sy=0,sz=0,sw=0, ez=0;

  for (long r = r0; r < r1; ++r) {
    int b = batch[r];
    if (b != cur) {
      float* ps = ns2s + (size_t)cur*DD + d0;
      atomicAdd(ps+0,sx); atomicAdd(ps+1,sy); atomicAdd(ps+2,sz); atomicAdd(ps+3,sw);
      if (lane == 0) atomicAdd(z2+cur, ez);
      sx=sy=sz=sw=0; ez=0;
      cur = b;
      qv = *(const float4*)(qs + (size_t)cur*DD + d0);
    }
    const float4 v = *(const float4*)(x + (size_t)r*DD + d0);
    float p = v.x*qv.x + v.y*qv.y + v.z*qv.z + v.w*qv.w;
    #pragma unroll
    for (int o = 32; o; o >>= 1) p += __shfl_xor(p, o);
    float e = expf(p);   // |logit| << 1, unstabilized exp is safe & exact under softmax
    sx += v.x*e; sy += v.y*e; sz += v.z*e; sw += v.w*e;
    ez += e;
  }
  {
    float* ps = ns2s + (size_t)cur*DD + d0;
    atomicAdd(ps+0,sx); atomicAdd(ps+1,sy); atomicAdd(ps+2,sz); atomicAdd(ps+3,sw);
    if (lane == 0) atomicAdd(z2+cur, ez);
  }
}

__global__ void k_mean(const float* __restrict__ hsum, const float* __restrict__ counts,
                       float* __restrict__ hmean) {
  int i = blockIdx.x * blockDim.x + threadIdx.x;
  hmean[i] = hsum[i] / counts[i >> 8];
}

__global__ void k_finalize(const float* __restrict__ hsum, const unsigned* __restrict__ hmaxk,
                           const float* __restrict__ natt, const float* __restrict__ ns2s,
                           const float* __restrict__ counts, const float* __restrict__ z1,
                           const float* __restrict__ z2, const float* __restrict__ hmean,
                           float* __restrict__ u, float* __restrict__ comb) {
  int i = blockIdx.x * blockDim.x + threadIdx.x;
  int g = i >> 8, d = i & 255;
  size_t c0 = (size_t)g * 1280;
  comb[c0 +        d] = hmean[i];
  comb[c0 +  256 + d] = funkey(hmaxk[i]);
  comb[c0 +  512 + d] = hsum[i];
  comb[c0 +  768 + d] = natt[i] / z1[g];
  u[i] = ns2s[i] / z2[g];
}

// ---------------- generic f32 tiled GEMM: C = act(scale*A@Bv + bias) ----------------
// Bv(k,n) = BT ? B[n*K+k] : B[k*Nn+n].  M,Nn multiples of 64, K multiple of 16.
template<int BT, int ACT>
__global__ __launch_bounds__(256) void gemm64(
    const float* __restrict__ A, const float* __restrict__ B,
    const float* __restrict__ bias, float* __restrict__ C,
    int M, int Nn, int K, int ldc, float scale)
{
  __shared__ float As[16][68];
  __shared__ float Bs[16][68];
  const int tx = threadIdx.x & 15;
  const int ty = threadIdx.x >> 4;
  const int row0 = blockIdx.y * 64;
  const int col0 = blockIdx.x * 64;
  float acc[4][4] = {};

  for (int k0 = 0; k0 < K; k0 += 16) {
    #pragma unroll
    for (int i = 0; i < 4; ++i) {
      int idx = threadIdx.x + i * 256;
      int m = idx >> 4, kk = idx & 15;
      As[kk][m] = A[(size_t)(row0 + m) * K + k0 + kk];
    }
    if (BT) {
      #pragma unroll
      for (int i = 0; i < 4; ++i) {
        int idx = threadIdx.x + i * 256;
        int n = idx >> 4, kk = idx & 15;
        Bs[kk][n] = B[(size_t)(col0 + n) * K + k0 + kk];
      }
    } else {
      #pragma unroll
      for (int i = 0; i < 4; ++i) {
        int idx = threadIdx.x + i * 256;
        int kk = idx >> 6, n = idx & 63;
        Bs[kk][n] = B[(size_t)(k0 + kk) * Nn + col0 + n];
      }
    }
    __syncthreads();
    #pragma unroll
    for (int kk = 0; kk < 16; ++kk) {
      float4 a4 = *(const float4*)&As[kk][ty * 4];
      float4 b4 = *(const float4*)&Bs[kk][tx * 4];
      float av[4] = {a4.x, a4.y, a4.z, a4.w};
      float bv[4] = {b4.x, b4.y, b4.z, b4.w};
      #pragma unroll
      for (int i = 0; i < 4; ++i)
        #pragma unroll
        for (int j = 0; j < 4; ++j) acc[i][j] += av[i] * bv[j];
    }
    __syncthreads();
  }
  #pragma unroll
  for (int i = 0; i < 4; ++i) {
    int m = row0 + ty * 4 + i;
    #pragma unroll
    for (int j = 0; j < 4; ++j) {
      int n = col0 + tx * 4 + j;
      float v = acc[i][j] * scale + (bias ? bias[n] : 0.f);
      if (ACT) v = 0.5f * v * (1.f + erff(v * 0.70710678118654752f));
      C[(size_t)m * ldc + n] = v;
    }
  }
}

extern "C" void kernel_launch(void* const* d_in, const int* in_sizes, int n_in,
                              void* d_out, int out_size, void* d_ws, size_t ws_size,
                              hipStream_t stream)
{
  (void)n_in; (void)out_size; (void)ws_size;
  const float* x      = (const float*)d_in[0];
  const int*   batch  = (const int*)d_in[1];
  const float* w_attn = (const float*)d_in[3];
  // d_in[4] = b_attn: softmax shift-invariant, unused
  const float* Wq     = (const float*)d_in[5];
  const float* bq     = (const float*)d_in[6];
  const float* Wk     = (const float*)d_in[7];
  const float* bk     = (const float*)d_in[8];
  const float* W1     = (const float*)d_in[9];
  const float* b1     = (const float*)d_in[10];
  const float* W2     = (const float*)d_in[11];
  const float* b2     = (const float*)d_in[12];
  float* out = (float*)d_out;
  const int N = in_sizes[0] / DD;

  float* ws = (float*)d_ws;
  const size_t GD = (size_t)GG * DD;
  float*    hsum   = ws;
  unsigned* hmaxk  = (unsigned*)(ws + GD);
  float*    natt   = ws + 2 * GD;
  float*    ns2s   = ws + 3 * GD;
  float*    counts = ws + 4 * GD;
  float*    z1     = counts + GG;
  float*    z2     = z1 + GG;
  float*    hmean  = z2 + GG;
  float*    q      = hmean + GD;
  float*    qs     = q + GD;
  float*    u      = qs + GD;
  float*    comb   = u + GD;                  // GG x 1280
  float*    h1     = comb + (size_t)GG * 1280; // GG x 512

  const int nzero = (int)(4 * GD + 3 * GG);
  k_zero<<<(nzero + 255) / 256, 256, 0, stream>>>(ws, nzero);

  const int RPW = 64;
  const int waves = (N + RPW - 1) / RPW;
  const int pblocks = (waves + 3) / 4;

  k_pass1<<<pblocks, 256, 0, stream>>>(x, batch, w_attn, hsum, hmaxk, counts, z1, natt, N, RPW);
  k_mean<<<(int)(GD / 256), 256, 0, stream>>>(hsum, counts, hmean);
  // q = h_mean @ Wq + bq
  gemm64<0,0><<<dim3(DD/64, GG/64), 256, 0, stream>>>(hmean, Wq, bq, q, GG, DD, DD, DD, 1.0f);
  // qs = (q @ Wk^T) / 16
  gemm64<1,0><<<dim3(DD/64, GG/64), 256, 0, stream>>>(q, Wk, nullptr, qs, GG, DD, DD, DD, 0.0625f);
  k_pass2<<<pblocks, 256, 0, stream>>>(x, batch, qs, z2, ns2s, N, RPW);
  k_finalize<<<(int)(GD / 256), 256, 0, stream>>>(hsum, hmaxk, natt, ns2s, counts, z1, z2, hmean, u, comb);
  // h_s2s = u @ Wk + bk  -> comb cols [1024,1280)
  gemm64<0,0><<<dim3(DD/64, GG/64), 256, 0, stream>>>(u, Wk, bk, comb + 4*DD, GG, DD, DD, 5*DD, 1.0f);
  // h1 = gelu(comb @ W1 + b1)
  gemm64<0,1><<<dim3(512/64, GG/64), 256, 0, stream>>>(comb, W1, b1, h1, GG, 512, 5*DD, 512, 1.0f);
  // out = h1 @ W2 + b2
  gemm64<0,0><<<dim3(DD/64, GG/64), 256, 0, stream>>>(h1, W2, b2, out, GG, DD, 512, DD, 1.0f);
}

// Round 2
// 357.647 us; speedup vs baseline: 1.3389x; 1.3389x over previous
//
#include <hip/hip_runtime.h>
#include <math.h>

#define DD 256
#define GG 2048

typedef __attribute__((ext_vector_type(8))) short short8;
typedef __attribute__((ext_vector_type(4))) float f32x4;

__device__ __forceinline__ unsigned fkey(float f) {
  unsigned u = __float_as_uint(f);
  return (u & 0x80000000u) ? ~u : (u | 0x80000000u);
}
__device__ __forceinline__ float funkey(unsigned k) {
  unsigned u = (k & 0x80000000u) ? (k & 0x7fffffffu) : ~k;
  return __uint_as_float(u);
}
__device__ __forceinline__ unsigned short f2b(float f) {  // RNE f32->bf16
  unsigned u = __float_as_uint(f);
  return (unsigned short)((u + 0x7fffu + ((u >> 16) & 1u)) >> 16);
}

__global__ void k_zero(float* __restrict__ p, int n) {
  int i = blockIdx.x * blockDim.x + threadIdx.x;
  if (i < n) p[i] = 0.f;
}

// convert weights to bf16; transposed (K-contiguous) layouts for MFMA B operands
__global__ void k_prep(const float* __restrict__ Wq, const float* __restrict__ Wk,
                       const float* __restrict__ W1, const float* __restrict__ W2,
                       unsigned short* __restrict__ Wq_b, unsigned short* __restrict__ Wk_b,
                       unsigned short* __restrict__ WkT_b, unsigned short* __restrict__ W1T_b,
                       unsigned short* __restrict__ W2T_b) {
  int i = blockIdx.x * blockDim.x + threadIdx.x;
  if (i < 65536) { Wq_b[i] = f2b(Wq[i]); return; }
  i -= 65536;
  if (i < 65536) { Wk_b[i] = f2b(Wk[i]); return; }
  i -= 65536;
  if (i < 65536) { int n = i >> 8, k = i & 255; WkT_b[i] = f2b(Wk[k * 256 + n]); return; }
  i -= 65536;
  if (i < 655360) { int n = i / 1280, k = i % 1280; W1T_b[i] = f2b(W1[k * 512 + n]); return; }
  i -= 655360;
  if (i < 131072) { int n = i >> 9, k = i & 511; W2T_b[i] = f2b(W2[k * 256 + n]); return; }
}

// bqk[a] = sum_b bq[b]*Wk[a][b] / 16
__global__ void k_bqk(const float* __restrict__ bq, const float* __restrict__ Wk,
                      float* __restrict__ bqk) {
  int a = threadIdx.x;
  float s = 0.f;
  for (int b = 0; b < 256; ++b) s += bq[b] * Wk[(size_t)a * 256 + b];
  bqk[a] = s * 0.0625f;
}

// ---------------- pass 1: h_sum, counts, h_max, attn softmax-pool ----------------
__global__ __launch_bounds__(256) void k_pass1(
    const float* __restrict__ x, const int* __restrict__ batch,
    const float* __restrict__ w_attn,
    float* __restrict__ hsum, unsigned* __restrict__ hmaxk,
    float* __restrict__ counts, float* __restrict__ z1,
    float* __restrict__ natt, int N, int rowsPerWave)
{
  const int lane = threadIdx.x & 63;
  const int wave = blockIdx.x * (blockDim.x >> 6) + (threadIdx.x >> 6);
  long r0 = (long)wave * rowsPerWave;
  if (r0 >= N) return;
  long r1 = r0 + rowsPerWave; if (r1 > N) r1 = N;
  const int d0 = lane * 4;
  const float4 wa = *(const float4*)(w_attn + d0);

  float sx=0,sy=0,sz=0,sw=0;
  float ax=0,ay=0,az=0,aw=0;
  const float NEG = -3.402823466e38f;
  float mx=NEG,my=NEG,mz=NEG,mw=NEG;
  float cnt=0.f, ez=0.f;
  int cur = batch[r0];

  for (long r = r0; r < r1; ++r) {
    int b = batch[r];
    if (b != cur) {
      float* ps = hsum + (size_t)cur*DD + d0;
      atomicAdd(ps+0,sx); atomicAdd(ps+1,sy); atomicAdd(ps+2,sz); atomicAdd(ps+3,sw);
      unsigned* pm = hmaxk + (size_t)cur*DD + d0;
      atomicMax(pm+0,fkey(mx)); atomicMax(pm+1,fkey(my));
      atomicMax(pm+2,fkey(mz)); atomicMax(pm+3,fkey(mw));
      float* pa = natt + (size_t)cur*DD + d0;
      atomicAdd(pa+0,ax); atomicAdd(pa+1,ay); atomicAdd(pa+2,az); atomicAdd(pa+3,aw);
      if (lane == 0) { atomicAdd(counts+cur,cnt); atomicAdd(z1+cur,ez); }
      sx=sy=sz=sw=0; ax=ay=az=aw=0; mx=my=mz=mw=NEG; cnt=0; ez=0;
      cur = b;
    }
    const float4 v = *(const float4*)(x + (size_t)r*DD + d0);
    float p = v.x*wa.x + v.y*wa.y + v.z*wa.z + v.w*wa.w;
    #pragma unroll
    for (int o = 32; o; o >>= 1) p += __shfl_xor(p, o);
    float e = expf(p);   // softmax shift-invariance: unstabilized exp is exact here
    sx += v.x; sy += v.y; sz += v.z; sw += v.w;
    mx = fmaxf(mx,v.x); my = fmaxf(my,v.y); mz = fmaxf(mz,v.z); mw = fmaxf(mw,v.w);
    ax += v.x*e; ay += v.y*e; az += v.z*e; aw += v.w*e;
    cnt += 1.f; ez += e;
  }
  {
    float* ps = hsum + (size_t)cur*DD + d0;
    atomicAdd(ps+0,sx); atomicAdd(ps+1,sy); atomicAdd(ps+2,sz); atomicAdd(ps+3,sw);
    unsigned* pm = hmaxk + (size_t)cur*DD + d0;
    atomicMax(pm+0,fkey(mx)); atomicMax(pm+1,fkey(my));
    atomicMax(pm+2,fkey(mz)); atomicMax(pm+3,fkey(mw));
    float* pa = natt + (size_t)cur*DD + d0;
    atomicAdd(pa+0,ax); atomicAdd(pa+1,ay); atomicAdd(pa+2,az); atomicAdd(pa+3,aw);
    if (lane == 0) { atomicAdd(counts+cur,cnt); atomicAdd(z1+cur,ez); }
  }
}

// ---------------- pass 2: s2s softmax-pool via qs ----------------
__global__ __launch_bounds__(256) void k_pass2(
    const float* __restrict__ x, const int* __restrict__ batch,
    const float* __restrict__ qs,
    float* __restrict__ z2, float* __restrict__ ns2s, int N, int rowsPerWave)
{
  const int lane = threadIdx.x & 63;
  const int wave = blockIdx.x * (blockDim.x >> 6) + (threadIdx.x >> 6);
  long r0 = (long)wave * rowsPerWave;
  if (r0 >= N) return;
  long r1 = r0 + rowsPerWave; if (r1 > N) r1 = N;
  const int d0 = lane * 4;

  int cur = batch[r0];
  float4 qv = *(const float4*)(qs + (size_t)cur*DD + d0);
  float sx=0,sy=0,sz=0,sw=0, ez=0;

  for (long r = r0; r < r1; ++r) {
    int b = batch[r];
    if (b != cur) {
      float* ps = ns2s + (size_t)cur*DD + d0;
      atomicAdd(ps+0,sx); atomicAdd(ps+1,sy); atomicAdd(ps+2,sz); atomicAdd(ps+3,sw);
      if (lane == 0) atomicAdd(z2+cur, ez);
      sx=sy=sz=sw=0; ez=0;
      cur = b;
      qv = *(const float4*)(qs + (size_t)cur*DD + d0);
    }
    const float4 v = *(const float4*)(x + (size_t)r*DD + d0);
    float p = v.x*qv.x + v.y*qv.y + v.z*qv.z + v.w*qv.w;
    #pragma unroll
    for (int o = 32; o; o >>= 1) p += __shfl_xor(p, o);
    float e = expf(p);
    sx += v.x*e; sy += v.y*e; sz += v.z*e; sw += v.w*e;
    ez += e;
  }
  {
    float* ps = ns2s + (size_t)cur*DD + d0;
    atomicAdd(ps+0,sx); atomicAdd(ps+1,sy); atomicAdd(ps+2,sz); atomicAdd(ps+3,sw);
    if (lane == 0) atomicAdd(z2+cur, ez);
  }
}

__global__ void k_mean_b(const float* __restrict__ hsum, const float* __restrict__ counts,
                         unsigned short* __restrict__ hmean_b) {
  int i = blockIdx.x * blockDim.x + threadIdx.x;
  hmean_b[i] = f2b(hsum[i] / counts[i >> 8]);
}

__global__ void k_finalize(const float* __restrict__ hsum, const unsigned* __restrict__ hmaxk,
                           const float* __restrict__ natt, const float* __restrict__ ns2s,
                           const float* __restrict__ counts, const float* __restrict__ z1,
                           const float* __restrict__ z2,
                           unsigned short* __restrict__ u_b, unsigned short* __restrict__ comb_b) {
  int i = blockIdx.x * blockDim.x + threadIdx.x;
  int g = i >> 8, d = i & 255;
  size_t c0 = (size_t)g * 1280;
  comb_b[c0 +        d] = f2b(hsum[i] / counts[g]);
  comb_b[c0 +  256 + d] = f2b(funkey(hmaxk[i]));
  comb_b[c0 +  512 + d] = f2b(hsum[i]);
  comb_b[c0 +  768 + d] = f2b(natt[i] / z1[g]);
  u_b[i] = f2b(ns2s[i] / z2[g]);
}

// ---------------- bf16 MFMA GEMM, LDS-free direct fragments ----------------
// A_b: [M][K] bf16 row-major; B_b: [N][K] bf16 row-major (i.e. op-B transposed).
// C = act(scale*A@B^T + bias).  OUT: 0 = f32 store, 1 = bf16 store, 2 = bf16 transposed store.
// M,N multiples of 64; K multiple of 32.
template<int ACT, int OUT>
__global__ __launch_bounds__(256) void gemm_mfma(
    const unsigned short* __restrict__ Ab, const unsigned short* __restrict__ Bb,
    const float* __restrict__ bias, void* __restrict__ Cp,
    int K, int ldc, float scale)
{
  const int l  = threadIdx.x & 63;
  const int w  = threadIdx.x >> 6;
  const int m0 = blockIdx.y * 64 + (w >> 1) * 32;
  const int n0 = blockIdx.x * 64 + (w & 1) * 32;
  const int row = l & 15;
  const int kb  = (l >> 4) * 8;

  f32x4 acc00 = {}, acc01 = {}, acc10 = {}, acc11 = {};
  const unsigned short* pa0 = Ab + (size_t)(m0 + row) * K + kb;
  const unsigned short* pa1 = pa0 + (size_t)16 * K;
  const unsigned short* pb0 = Bb + (size_t)(n0 + row) * K + kb;
  const unsigned short* pb1 = pb0 + (size_t)16 * K;

  for (int k0 = 0; k0 < K; k0 += 32) {
    short8 a0 = *(const short8*)(pa0 + k0);
    short8 a1 = *(const short8*)(pa1 + k0);
    short8 b0 = *(const short8*)(pb0 + k0);
    short8 b1 = *(const short8*)(pb1 + k0);
    acc00 = __builtin_amdgcn_mfma_f32_16x16x32_bf16(a0, b0, acc00, 0, 0, 0);
    acc01 = __builtin_amdgcn_mfma_f32_16x16x32_bf16(a0, b1, acc01, 0, 0, 0);
    acc10 = __builtin_amdgcn_mfma_f32_16x16x32_bf16(a1, b0, acc10, 0, 0, 0);
    acc11 = __builtin_amdgcn_mfma_f32_16x16x32_bf16(a1, b1, acc11, 0, 0, 0);
  }

  f32x4 accs[2][2] = {{acc00, acc01}, {acc10, acc11}};
  #pragma unroll
  for (int i = 0; i < 2; ++i) {
    #pragma unroll
    for (int j = 0; j < 2; ++j) {
      int cn = n0 + 16 * j + (l & 15);
      float bv = bias ? bias[cn] : 0.f;
      #pragma unroll
      for (int r = 0; r < 4; ++r) {
        int cm = m0 + 16 * i + (l >> 4) * 4 + r;
        float v = accs[i][j][r] * scale + bv;
        if (ACT) v = 0.5f * v * (1.f + erff(v * 0.70710678118654752f));
        if (OUT == 0)      ((float*)Cp)[(size_t)cm * ldc + cn] = v;
        else if (OUT == 1) ((unsigned short*)Cp)[(size_t)cm * ldc + cn] = f2b(v);
        else               ((unsigned short*)Cp)[(size_t)cn * ldc + cm] = f2b(v);
      }
    }
  }
}

extern "C" void kernel_launch(void* const* d_in, const int* in_sizes, int n_in,
                              void* d_out, int out_size, void* d_ws, size_t ws_size,
                              hipStream_t stream)
{
  (void)n_in; (void)out_size; (void)ws_size;
  const float* x      = (const float*)d_in[0];
  const int*   batch  = (const int*)d_in[1];
  const float* w_attn = (const float*)d_in[3];
  // d_in[4] = b_attn: softmax shift-invariant, unused
  const float* Wq     = (const float*)d_in[5];
  const float* bq     = (const float*)d_in[6];
  const float* Wk     = (const float*)d_in[7];
  const float* bk     = (const float*)d_in[8];
  const float* W1     = (const float*)d_in[9];
  const float* b1     = (const float*)d_in[10];
  const float* W2     = (const float*)d_in[11];
  const float* b2     = (const float*)d_in[12];
  float* out = (float*)d_out;
  const int N = in_sizes[0] / DD;

  float* ws = (float*)d_ws;
  const size_t GD = (size_t)GG * DD;
  // f32 accumulators (zeroed)
  float*    hsum   = ws;                 // GD
  unsigned* hmaxk  = (unsigned*)(ws + GD);   // GD
  float*    natt   = ws + 2 * GD;        // GD
  float*    ns2s   = ws + 3 * GD;        // GD
  float*    counts = ws + 4 * GD;        // GG
  float*    z1     = counts + GG;        // GG
  float*    z2     = z1 + GG;            // GG
  // f32 scratch
  float*    qs     = z2 + GG;            // GD
  float*    bqk    = qs + GD;            // 256
  // bf16 scratch (sizes in float units = elems/2)
  unsigned short* hmean_b = (unsigned short*)(bqk + 256);        // GD bf16
  unsigned short* u_b     = hmean_b + GD;                        // GD
  unsigned short* comb_b  = u_b + GD;                            // GG*1280
  unsigned short* h1_b    = comb_b + (size_t)GG * 1280;          // GG*512
  unsigned short* Wq_b    = h1_b + (size_t)GG * 512;             // 65536
  unsigned short* Wk_b    = Wq_b + 65536;                        // 65536
  unsigned short* WkT_b   = Wk_b + 65536;                        // 65536
  unsigned short* MT_b    = WkT_b + 65536;                       // 65536
  unsigned short* W1T_b   = MT_b + 65536;                        // 655360
  unsigned short* W2T_b   = W1T_b + 655360;                      // 131072

  const int nzero = (int)(4 * GD + 3 * GG);
  k_zero<<<(nzero + 255) / 256, 256, 0, stream>>>(ws, nzero);
  k_prep<<<(983040 + 255) / 256, 256, 0, stream>>>(Wq, Wk, W1, W2, Wq_b, Wk_b, WkT_b, W1T_b, W2T_b);
  k_bqk<<<1, 256, 0, stream>>>(bq, Wk, bqk);
  // M = Wq @ Wk^T  (256x256, K=256) -> stored transposed bf16: MT_b[a][c] = M[c][a]
  gemm_mfma<0,2><<<dim3(4, 4), 256, 0, stream>>>(Wq_b, Wk_b, nullptr, MT_b, 256, 256, 1.0f);

  const int RPW = 64;
  const int waves = (N + RPW - 1) / RPW;
  const int pblocks = (waves + 3) / 4;

  k_pass1<<<pblocks, 256, 0, stream>>>(x, batch, w_attn, hsum, hmaxk, counts, z1, natt, N, RPW);
  k_mean_b<<<(int)(GD / 256), 256, 0, stream>>>(hsum, counts, hmean_b);
  // qs = hmean @ M / 16 + bqk   (2048x256, K=256)
  gemm_mfma<0,0><<<dim3(4, 32), 256, 0, stream>>>(hmean_b, MT_b, bqk, qs, 256, 256, 0.0625f);
  k_pass2<<<pblocks, 256, 0, stream>>>(x, batch, qs, z2, ns2s, N, RPW);
  k_finalize<<<(int)(GD / 256), 256, 0, stream>>>(hsum, hmaxk, natt, ns2s, counts, z1, z2, u_b, comb_b);
  // h_s2s = u @ Wk + bk -> comb cols [1024,1280), bf16   (2048x256, K=256)
  gemm_mfma<0,1><<<dim3(4, 32), 256, 0, stream>>>(u_b, WkT_b, bk, comb_b + 4 * DD, 256, 1280, 1.0f);
  // h1 = gelu(comb @ W1 + b1), bf16   (2048x512, K=1280)
  gemm_mfma<1,1><<<dim3(8, 32), 256, 0, stream>>>(comb_b, W1T_b, b1, h1_b, 1280, 512, 1.0f);
  // out = h1 @ W2 + b2, f32   (2048x256, K=512)
  gemm_mfma<0,0><<<dim3(4, 32), 256, 0, stream>>>(h1_b, W2T_b, b2, out, 512, 256, 1.0f);
}

// Round 3
// 237.896 us; speedup vs baseline: 2.0129x; 1.5034x over previous
//
#include <hip/hip_runtime.h>
#include <math.h>

#define DD 256
#define GG 2048

typedef __attribute__((ext_vector_type(8))) short short8;
typedef __attribute__((ext_vector_type(4))) float f32x4;

__device__ __forceinline__ unsigned short f2b(float f) {  // RNE f32->bf16
  unsigned u = __float_as_uint(f);
  return (unsigned short)((u + 0x7fffu + ((u >> 16) & 1u)) >> 16);
}

// convert weights to bf16; transposed (K-contiguous) layouts for MFMA B operands
__global__ void k_prep(const float* __restrict__ Wq, const float* __restrict__ Wk,
                       const float* __restrict__ W1, const float* __restrict__ W2,
                       unsigned short* __restrict__ Wq_b, unsigned short* __restrict__ Wk_b,
                       unsigned short* __restrict__ WkT_b, unsigned short* __restrict__ W1T_b,
                       unsigned short* __restrict__ W2T_b) {
  int i = blockIdx.x * blockDim.x + threadIdx.x;
  if (i < 65536) { Wq_b[i] = f2b(Wq[i]); return; }
  i -= 65536;
  if (i < 65536) { Wk_b[i] = f2b(Wk[i]); return; }
  i -= 65536;
  if (i < 65536) { int n = i >> 8, k = i & 255; WkT_b[i] = f2b(Wk[k * 256 + n]); return; }
  i -= 65536;
  if (i < 655360) { int n = i / 1280, k = i % 1280; W1T_b[i] = f2b(W1[k * 512 + n]); return; }
  i -= 655360;
  if (i < 131072) { int n = i >> 9, k = i & 511; W2T_b[i] = f2b(W2[k * 256 + n]); return; }
}

// bqk[a] = sum_b bq[b]*Wk[a][b] / 16   (one wave per output element)
__global__ void k_bqk(const float* __restrict__ bq, const float* __restrict__ Wk,
                      float* __restrict__ bqk) {
  int a = blockIdx.x;
  int lane = threadIdx.x;
  const float4 w = *(const float4*)(Wk + (size_t)a * 256 + lane * 4);
  const float4 b = *(const float4*)(bq + lane * 4);
  float p = w.x * b.x + w.y * b.y + w.z * b.z + w.w * b.w;
  #pragma unroll
  for (int o = 32; o; o >>= 1) p += __shfl_xor(p, o);
  if (lane == 0) bqk[a] = p * 0.0625f;
}

// segment offsets from sorted batch (every graph id present)
__global__ void k_offsets(const int* __restrict__ batch, int* __restrict__ offs, int N) {
  int i = blockIdx.x * blockDim.x + threadIdx.x;
  if (i >= N) return;
  if (i == 0) offs[0] = 0;
  else if (batch[i] != batch[i - 1]) offs[batch[i]] = i;
  if (i == N - 1) offs[GG] = N;
}

// ---------------- fused per-graph pooling: one block = one graph ----------------
__global__ __launch_bounds__(256, 2) void k_fused(
    const float* __restrict__ x, const int* __restrict__ offs,
    const float* __restrict__ w_attn, const float* __restrict__ M,
    const float* __restrict__ bqk,
    unsigned short* __restrict__ u_b, unsigned short* __restrict__ comb_b)
{
  const int g = blockIdx.x;
  const int s = offs[g], e = offs[g + 1];
  const int t = threadIdx.x;
  const int lane = t & 63, w = t >> 6;
  const int d0 = lane * 4;

  __shared__ float redA[4][256];   // sum / s2s-num
  __shared__ float redB[4][256];   // attn-num
  __shared__ float redC[4][256];   // max
  __shared__ float hm[256];
  __shared__ float qsL[256];
  __shared__ float zL[4], z2L[4];

  const float4 wa = *(const float4*)(w_attn + d0);
  const float NEG = -3.402823466e38f;

  // ---- phase A: stream rows from HBM; sum, max, attn softmax-pool ----
  float sx=0,sy=0,sz=0,sw=0, ax=0,ay=0,az=0,aw=0;
  float mx=NEG,my=NEG,mz=NEG,mw=NEG, ez=0.f;
  {
    int r = s + w;
    float4 v = (r < e) ? *(const float4*)(x + (size_t)r * DD + d0)
                       : (float4){0,0,0,0};
    while (r < e) {
      int rn = r + 4;
      float4 vn = (rn < e) ? *(const float4*)(x + (size_t)rn * DD + d0)
                           : (float4){0,0,0,0};
      float p = v.x*wa.x + v.y*wa.y + v.z*wa.z + v.w*wa.w;
      #pragma unroll
      for (int o = 32; o; o >>= 1) p += __shfl_xor(p, o);
      float ee = expf(p);       // softmax shift-invariance: unstabilized exp exact
      sx += v.x; sy += v.y; sz += v.z; sw += v.w;
      mx = fmaxf(mx, v.x); my = fmaxf(my, v.y);
      mz = fmaxf(mz, v.z); mw = fmaxf(mw, v.w);
      ax += v.x*ee; ay += v.y*ee; az += v.z*ee; aw += v.w*ee;
      ez += ee;
      v = vn; r = rn;
    }
  }
  { float* p = &redA[w][d0]; p[0]=sx; p[1]=sy; p[2]=sz; p[3]=sw; }
  { float* p = &redB[w][d0]; p[0]=ax; p[1]=ay; p[2]=az; p[3]=aw; }
  { float* p = &redC[w][d0]; p[0]=mx; p[1]=my; p[2]=mz; p[3]=mw; }
  if (lane == 0) zL[w] = ez;
  __syncthreads();

  const float cnt = (float)(e - s);
  {
    float s4 = redA[0][t] + redA[1][t] + redA[2][t] + redA[3][t];
    float a4 = redB[0][t] + redB[1][t] + redB[2][t] + redB[3][t];
    float m4 = fmaxf(fmaxf(redC[0][t], redC[1][t]), fmaxf(redC[2][t], redC[3][t]));
    float z1 = zL[0] + zL[1] + zL[2] + zL[3];
    float hmean = s4 / cnt;
    hm[t] = hmean;
    size_t c0 = (size_t)g * 1280;
    comb_b[c0 +        t] = f2b(hmean);
    comb_b[c0 +  256 + t] = f2b(m4);
    comb_b[c0 +  512 + t] = f2b(s4);
    comb_b[c0 +  768 + t] = f2b(a4 / z1);
  }
  __syncthreads();

  // ---- phase B: qs = hm @ M / 16 + bqk  (M is 256KB, L2-hot) ----
  {
    float acc = 0.f;
    #pragma unroll 8
    for (int a = 0; a < 256; ++a) acc += hm[a] * M[(size_t)a * 256 + t];
    qsL[t] = acc * 0.0625f + bqk[t];
  }
  __syncthreads();

  // ---- phase C: re-read rows (L3/L2-hot); s2s softmax-pool ----
  float nx=0,ny=0,nz=0,nw=0, ez2=0.f;
  {
    const float4 qv = *(const float4*)&qsL[d0];
    int r = s + w;
    float4 v = (r < e) ? *(const float4*)(x + (size_t)r * DD + d0)
                       : (float4){0,0,0,0};
    while (r < e) {
      int rn = r + 4;
      float4 vn = (rn < e) ? *(const float4*)(x + (size_t)rn * DD + d0)
                           : (float4){0,0,0,0};
      float p = v.x*qv.x + v.y*qv.y + v.z*qv.z + v.w*qv.w;
      #pragma unroll
      for (int o = 32; o; o >>= 1) p += __shfl_xor(p, o);
      float ee = expf(p);
      nx += v.x*ee; ny += v.y*ee; nz += v.z*ee; nw += v.w*ee;
      ez2 += ee;
      v = vn; r = rn;
    }
  }
  { float* p = &redA[w][d0]; p[0]=nx; p[1]=ny; p[2]=nz; p[3]=nw; }
  if (lane == 0) z2L[w] = ez2;
  __syncthreads();
  {
    float n4 = redA[0][t] + redA[1][t] + redA[2][t] + redA[3][t];
    float z2 = z2L[0] + z2L[1] + z2L[2] + z2L[3];
    u_b[(size_t)g * DD + t] = f2b(n4 / z2);
  }
}

// ---------------- bf16 MFMA GEMM, LDS-free direct fragments ----------------
// A_b: [M][K] bf16 row-major; B_b: [N][K] bf16 row-major (op-B transposed).
// C = act(scale*A@B^T + bias).  OUT: 0 = f32 store, 1 = bf16 store.
template<int ACT, int OUT>
__global__ __launch_bounds__(256) void gemm_mfma(
    const unsigned short* __restrict__ Ab, const unsigned short* __restrict__ Bb,
    const float* __restrict__ bias, void* __restrict__ Cp,
    int K, int ldc, float scale)
{
  const int l  = threadIdx.x & 63;
  const int w  = threadIdx.x >> 6;
  const int m0 = blockIdx.y * 64 + (w >> 1) * 32;
  const int n0 = blockIdx.x * 64 + (w & 1) * 32;
  const int row = l & 15;
  const int kb  = (l >> 4) * 8;

  f32x4 acc00 = {}, acc01 = {}, acc10 = {}, acc11 = {};
  const unsigned short* pa0 = Ab + (size_t)(m0 + row) * K + kb;
  const unsigned short* pa1 = pa0 + (size_t)16 * K;
  const unsigned short* pb0 = Bb + (size_t)(n0 + row) * K + kb;
  const unsigned short* pb1 = pb0 + (size_t)16 * K;

  for (int k0 = 0; k0 < K; k0 += 32) {
    short8 a0 = *(const short8*)(pa0 + k0);
    short8 a1 = *(const short8*)(pa1 + k0);
    short8 b0 = *(const short8*)(pb0 + k0);
    short8 b1 = *(const short8*)(pb1 + k0);
    acc00 = __builtin_amdgcn_mfma_f32_16x16x32_bf16(a0, b0, acc00, 0, 0, 0);
    acc01 = __builtin_amdgcn_mfma_f32_16x16x32_bf16(a0, b1, acc01, 0, 0, 0);
    acc10 = __builtin_amdgcn_mfma_f32_16x16x32_bf16(a1, b0, acc10, 0, 0, 0);
    acc11 = __builtin_amdgcn_mfma_f32_16x16x32_bf16(a1, b1, acc11, 0, 0, 0);
  }

  f32x4 accs[2][2] = {{acc00, acc01}, {acc10, acc11}};
  #pragma unroll
  for (int i = 0; i < 2; ++i) {
    #pragma unroll
    for (int j = 0; j < 2; ++j) {
      int cn = n0 + 16 * j + (l & 15);
      float bv = bias ? bias[cn] : 0.f;
      #pragma unroll
      for (int r = 0; r < 4; ++r) {
        int cm = m0 + 16 * i + (l >> 4) * 4 + r;
        float v = accs[i][j][r] * scale + bv;
        if (ACT) v = 0.5f * v * (1.f + erff(v * 0.70710678118654752f));
        if (OUT == 0)      ((float*)Cp)[(size_t)cm * ldc + cn] = v;
        else               ((unsigned short*)Cp)[(size_t)cm * ldc + cn] = f2b(v);
      }
    }
  }
}

extern "C" void kernel_launch(void* const* d_in, const int* in_sizes, int n_in,
                              void* d_out, int out_size, void* d_ws, size_t ws_size,
                              hipStream_t stream)
{
  (void)n_in; (void)out_size; (void)ws_size;
  const float* x      = (const float*)d_in[0];
  const int*   batch  = (const int*)d_in[1];
  const float* w_attn = (const float*)d_in[3];
  // d_in[4] = b_attn: softmax shift-invariant, unused
  const float* Wq     = (const float*)d_in[5];
  const float* bq     = (const float*)d_in[6];
  const float* Wk     = (const float*)d_in[7];
  const float* bk     = (const float*)d_in[8];
  const float* W1     = (const float*)d_in[9];
  const float* b1     = (const float*)d_in[10];
  const float* W2     = (const float*)d_in[11];
  const float* b2     = (const float*)d_in[12];
  float* out = (float*)d_out;
  const int N = in_sizes[0] / DD;

  float* ws = (float*)d_ws;
  float* M    = ws;                         // 256x256 f32
  float* bqk  = ws + 65536;                 // 256
  int*   offs = (int*)(ws + 65536 + 256);   // 2049 ints (pad to 2304 floats)
  float* base = ws + 65536 + 256 + 2304;
  unsigned short* u_b    = (unsigned short*)base;            // 2048*256 bf16
  unsigned short* comb_b = u_b + (size_t)GG * DD;            // 2048*1280
  unsigned short* h1_b   = comb_b + (size_t)GG * 1280;       // 2048*512
  unsigned short* Wq_b   = h1_b + (size_t)GG * 512;          // 65536
  unsigned short* Wk_b   = Wq_b + 65536;                     // 65536
  unsigned short* WkT_b  = Wk_b + 65536;                     // 65536
  unsigned short* W1T_b  = WkT_b + 65536;                    // 655360
  unsigned short* W2T_b  = W1T_b + 655360;                   // 131072

  k_prep<<<(983040 + 255) / 256, 256, 0, stream>>>(Wq, Wk, W1, W2, Wq_b, Wk_b, WkT_b, W1T_b, W2T_b);
  k_bqk<<<256, 64, 0, stream>>>(bq, Wk, bqk);
  k_offsets<<<(N + 255) / 256, 256, 0, stream>>>(batch, offs, N);
  // M = Wq @ Wk^T  (256x256, K=256), f32
  gemm_mfma<0,0><<<dim3(4, 4), 256, 0, stream>>>(Wq_b, Wk_b, nullptr, M, 256, 256, 1.0f);
  // fused per-graph pooling (writes comb cols 0..1023 and u)
  k_fused<<<GG, 256, 0, stream>>>(x, offs, w_attn, M, bqk, u_b, comb_b);
  // h_s2s = u @ Wk + bk -> comb cols [1024,1280), bf16
  gemm_mfma<0,1><<<dim3(4, 32), 256, 0, stream>>>(u_b, WkT_b, bk, comb_b + 4 * DD, 256, 1280, 1.0f);
  // h1 = gelu(comb @ W1 + b1), bf16
  gemm_mfma<1,1><<<dim3(8, 32), 256, 0, stream>>>(comb_b, W1T_b, b1, h1_b, 1280, 512, 1.0f);
  // out = h1 @ W2 + b2, f32
  gemm_mfma<0,0><<<dim3(4, 32), 256, 0, stream>>>(h1_b, W2T_b, b2, out, 512, 256, 1.0f);
}

// Round 4
// 221.464 us; speedup vs baseline: 2.1622x; 1.0742x over previous
//
#include <hip/hip_runtime.h>
#include <math.h>

#define DD 256
#define GG 2048

typedef __attribute__((ext_vector_type(8))) short short8;
typedef __attribute__((ext_vector_type(4))) float f32x4;

__device__ __forceinline__ unsigned short f2b(float f) {  // RNE f32->bf16
  unsigned u = __float_as_uint(f);
  return (unsigned short)((u + 0x7fffu + ((u >> 16) & 1u)) >> 16);
}

// convert weights to bf16; transposed (K-contiguous) layouts for MFMA B operands
__global__ void k_prep(const float* __restrict__ Wq, const float* __restrict__ Wk,
                       const float* __restrict__ W1, const float* __restrict__ W2,
                       unsigned short* __restrict__ Wq_b, unsigned short* __restrict__ Wk_b,
                       unsigned short* __restrict__ WkT_b, unsigned short* __restrict__ W1T_b,
                       unsigned short* __restrict__ W2T_b) {
  int i = blockIdx.x * blockDim.x + threadIdx.x;
  if (i < 65536) { Wq_b[i] = f2b(Wq[i]); return; }
  i -= 65536;
  if (i < 65536) { Wk_b[i] = f2b(Wk[i]); return; }
  i -= 65536;
  if (i < 65536) { int n = i >> 8, k = i & 255; WkT_b[i] = f2b(Wk[k * 256 + n]); return; }
  i -= 65536;
  if (i < 655360) { int n = i / 1280, k = i % 1280; W1T_b[i] = f2b(W1[k * 512 + n]); return; }
  i -= 655360;
  if (i < 131072) { int n = i >> 9, k = i & 511; W2T_b[i] = f2b(W2[k * 256 + n]); return; }
}

// bqk[a] = sum_b bq[b]*Wk[a][b] / 16   (one wave per output element)
__global__ void k_bqk(const float* __restrict__ bq, const float* __restrict__ Wk,
                      float* __restrict__ bqk) {
  int a = blockIdx.x;
  int lane = threadIdx.x;
  const float4 w = *(const float4*)(Wk + (size_t)a * 256 + lane * 4);
  const float4 b = *(const float4*)(bq + lane * 4);
  float p = w.x * b.x + w.y * b.y + w.z * b.z + w.w * b.w;
  #pragma unroll
  for (int o = 32; o; o >>= 1) p += __shfl_xor(p, o);
  if (lane == 0) bqk[a] = p * 0.0625f;
}

// segment offsets from sorted batch (every graph id present)
__global__ void k_offsets(const int* __restrict__ batch, int* __restrict__ offs, int N) {
  int i = blockIdx.x * blockDim.x + threadIdx.x;
  if (i >= N) return;
  if (i == 0) offs[0] = 0;
  else if (batch[i] != batch[i - 1]) offs[batch[i]] = i;
  if (i == N - 1) offs[GG] = N;
}

// ---------------- fused per-graph pooling: one block = one graph ----------------
// 4 blocks/CU + 4-deep row pipeline per wave: ~64 KB in flight per CU.
__global__ __launch_bounds__(256, 4) void k_fused(
    const float* __restrict__ x, const int* __restrict__ offs,
    const float* __restrict__ w_attn, const float* __restrict__ M,
    const float* __restrict__ bqk,
    unsigned short* __restrict__ u_b, unsigned short* __restrict__ comb_b)
{
  const int g = blockIdx.x;
  const int s = offs[g], e = offs[g + 1];
  const int t = threadIdx.x;
  const int lane = t & 63, w = t >> 6;
  const int d0 = lane * 4;

  __shared__ float redA[4][256];   // sum / s2s-num
  __shared__ float redB[4][256];   // attn-num
  __shared__ float redC[4][256];   // max
  __shared__ float hm[256];
  __shared__ float qsL[256];
  __shared__ float zL[4], z2L[4];

  const float4 wa = *(const float4*)(w_attn + d0);
  const float NEG = -3.402823466e38f;
  const float4 Z4 = {0, 0, 0, 0};

  // ---- phase A: stream rows from HBM; sum, max, attn softmax-pool ----
  float sx=0,sy=0,sz=0,sw=0, ax=0,ay=0,az=0,aw=0;
  float mx=NEG,my=NEG,mz=NEG,mw=NEG, ez=0.f;
  {
    int r = s + w;
    float4 b0 = (r      < e) ? *(const float4*)(x + (size_t)(r     ) * DD + d0) : Z4;
    float4 b1 = (r + 4  < e) ? *(const float4*)(x + (size_t)(r +  4) * DD + d0) : Z4;
    float4 b2 = (r + 8  < e) ? *(const float4*)(x + (size_t)(r +  8) * DD + d0) : Z4;
    float4 b3 = (r + 12 < e) ? *(const float4*)(x + (size_t)(r + 12) * DD + d0) : Z4;
    while (r < e) {
      const int rn = r + 16;
      float4 n0 = (rn      < e) ? *(const float4*)(x + (size_t)(rn     ) * DD + d0) : Z4;
      float4 n1 = (rn + 4  < e) ? *(const float4*)(x + (size_t)(rn +  4) * DD + d0) : Z4;
      float4 n2 = (rn + 8  < e) ? *(const float4*)(x + (size_t)(rn +  8) * DD + d0) : Z4;
      float4 n3 = (rn + 12 < e) ? *(const float4*)(x + (size_t)(rn + 12) * DD + d0) : Z4;
      #pragma unroll
      for (int i = 0; i < 4; ++i) {
        float4 v = (i == 0) ? b0 : (i == 1) ? b1 : (i == 2) ? b2 : b3;
        if (r + 4 * i < e) {        // wave-uniform guard
          float p = v.x*wa.x + v.y*wa.y + v.z*wa.z + v.w*wa.w;
          #pragma unroll
          for (int o = 32; o; o >>= 1) p += __shfl_xor(p, o);
          float ee = expf(p);       // softmax shift-invariance: unstabilized exp exact
          sx += v.x; sy += v.y; sz += v.z; sw += v.w;
          mx = fmaxf(mx, v.x); my = fmaxf(my, v.y);
          mz = fmaxf(mz, v.z); mw = fmaxf(mw, v.w);
          ax += v.x*ee; ay += v.y*ee; az += v.z*ee; aw += v.w*ee;
          ez += ee;
        }
      }
      b0 = n0; b1 = n1; b2 = n2; b3 = n3;
      r = rn;
    }
  }
  { float* p = &redA[w][d0]; p[0]=sx; p[1]=sy; p[2]=sz; p[3]=sw; }
  { float* p = &redB[w][d0]; p[0]=ax; p[1]=ay; p[2]=az; p[3]=aw; }
  { float* p = &redC[w][d0]; p[0]=mx; p[1]=my; p[2]=mz; p[3]=mw; }
  if (lane == 0) zL[w] = ez;
  __syncthreads();

  const float cnt = (float)(e - s);
  {
    float s4 = redA[0][t] + redA[1][t] + redA[2][t] + redA[3][t];
    float a4 = redB[0][t] + redB[1][t] + redB[2][t] + redB[3][t];
    float m4 = fmaxf(fmaxf(redC[0][t], redC[1][t]), fmaxf(redC[2][t], redC[3][t]));
    float z1 = zL[0] + zL[1] + zL[2] + zL[3];
    float hmean = s4 / cnt;
    hm[t] = hmean;
    size_t c0 = (size_t)g * 1280;
    comb_b[c0 +        t] = f2b(hmean);
    comb_b[c0 +  256 + t] = f2b(m4);
    comb_b[c0 +  512 + t] = f2b(s4);
    comb_b[c0 +  768 + t] = f2b(a4 / z1);
  }
  __syncthreads();

  // ---- phase B: qs = hm @ M / 16 + bqk  (M 256KB f32, L2-hot broadcast) ----
  {
    float acc = 0.f;
    #pragma unroll 8
    for (int a = 0; a < 256; ++a) acc += hm[a] * M[(size_t)a * 256 + t];
    qsL[t] = acc * 0.0625f + bqk[t];
  }
  __syncthreads();

  // ---- phase C: re-read rows (L3-hot); s2s softmax-pool ----
  float nx=0,ny=0,nz=0,nw=0, ez2=0.f;
  {
    const float4 qv = *(const float4*)&qsL[d0];
    int r = s + w;
    float4 b0 = (r      < e) ? *(const float4*)(x + (size_t)(r     ) * DD + d0) : Z4;
    float4 b1 = (r + 4  < e) ? *(const float4*)(x + (size_t)(r +  4) * DD + d0) : Z4;
    float4 b2 = (r + 8  < e) ? *(const float4*)(x + (size_t)(r +  8) * DD + d0) : Z4;
    float4 b3 = (r + 12 < e) ? *(const float4*)(x + (size_t)(r + 12) * DD + d0) : Z4;
    while (r < e) {
      const int rn = r + 16;
      float4 n0 = (rn      < e) ? *(const float4*)(x + (size_t)(rn     ) * DD + d0) : Z4;
      float4 n1 = (rn + 4  < e) ? *(const float4*)(x + (size_t)(rn +  4) * DD + d0) : Z4;
      float4 n2 = (rn + 8  < e) ? *(const float4*)(x + (size_t)(rn +  8) * DD + d0) : Z4;
      float4 n3 = (rn + 12 < e) ? *(const float4*)(x + (size_t)(rn + 12) * DD + d0) : Z4;
      #pragma unroll
      for (int i = 0; i < 4; ++i) {
        float4 v = (i == 0) ? b0 : (i == 1) ? b1 : (i == 2) ? b2 : b3;
        if (r + 4 * i < e) {        // wave-uniform guard
          float p = v.x*qv.x + v.y*qv.y + v.z*qv.z + v.w*qv.w;
          #pragma unroll
          for (int o = 32; o; o >>= 1) p += __shfl_xor(p, o);
          float ee = expf(p);
          nx += v.x*ee; ny += v.y*ee; nz += v.z*ee; nw += v.w*ee;
          ez2 += ee;
        }
      }
      b0 = n0; b1 = n1; b2 = n2; b3 = n3;
      r = rn;
    }
  }
  { float* p = &redA[w][d0]; p[0]=nx; p[1]=ny; p[2]=nz; p[3]=nw; }
  if (lane == 0) z2L[w] = ez2;
  __syncthreads();
  {
    float n4 = redA[0][t] + redA[1][t] + redA[2][t] + redA[3][t];
    float z2 = z2L[0] + z2L[1] + z2L[2] + z2L[3];
    u_b[(size_t)g * DD + t] = f2b(n4 / z2);
  }
}

// ---------------- bf16 MFMA GEMM, LDS-free direct fragments ----------------
// A_b: [M][K] bf16 row-major; B_b: [N][K] bf16 row-major (op-B transposed).
// C = act(scale*A@B^T + bias).  OUT: 0 = f32 store, 1 = bf16 store.
template<int ACT, int OUT>
__global__ __launch_bounds__(256) void gemm_mfma(
    const unsigned short* __restrict__ Ab, const unsigned short* __restrict__ Bb,
    const float* __restrict__ bias, void* __restrict__ Cp,
    int K, int ldc, float scale)
{
  const int l  = threadIdx.x & 63;
  const int w  = threadIdx.x >> 6;
  const int m0 = blockIdx.y * 64 + (w >> 1) * 32;
  const int n0 = blockIdx.x * 64 + (w & 1) * 32;
  const int row = l & 15;
  const int kb  = (l >> 4) * 8;

  f32x4 acc00 = {}, acc01 = {}, acc10 = {}, acc11 = {};
  const unsigned short* pa0 = Ab + (size_t)(m0 + row) * K + kb;
  const unsigned short* pa1 = pa0 + (size_t)16 * K;
  const unsigned short* pb0 = Bb + (size_t)(n0 + row) * K + kb;
  const unsigned short* pb1 = pb0 + (size_t)16 * K;

  for (int k0 = 0; k0 < K; k0 += 32) {
    short8 a0 = *(const short8*)(pa0 + k0);
    short8 a1 = *(const short8*)(pa1 + k0);
    short8 b0 = *(const short8*)(pb0 + k0);
    short8 b1 = *(const short8*)(pb1 + k0);
    acc00 = __builtin_amdgcn_mfma_f32_16x16x32_bf16(a0, b0, acc00, 0, 0, 0);
    acc01 = __builtin_amdgcn_mfma_f32_16x16x32_bf16(a0, b1, acc01, 0, 0, 0);
    acc10 = __builtin_amdgcn_mfma_f32_16x16x32_bf16(a1, b0, acc10, 0, 0, 0);
    acc11 = __builtin_amdgcn_mfma_f32_16x16x32_bf16(a1, b1, acc11, 0, 0, 0);
  }

  f32x4 accs[2][2] = {{acc00, acc01}, {acc10, acc11}};
  #pragma unroll
  for (int i = 0; i < 2; ++i) {
    #pragma unroll
    for (int j = 0; j < 2; ++j) {
      int cn = n0 + 16 * j + (l & 15);
      float bv = bias ? bias[cn] : 0.f;
      #pragma unroll
      for (int r = 0; r < 4; ++r) {
        int cm = m0 + 16 * i + (l >> 4) * 4 + r;
        float v = accs[i][j][r] * scale + bv;
        if (ACT) v = 0.5f * v * (1.f + erff(v * 0.70710678118654752f));
        if (OUT == 0)      ((float*)Cp)[(size_t)cm * ldc + cn] = v;
        else               ((unsigned short*)Cp)[(size_t)cm * ldc + cn] = f2b(v);
      }
    }
  }
}

extern "C" void kernel_launch(void* const* d_in, const int* in_sizes, int n_in,
                              void* d_out, int out_size, void* d_ws, size_t ws_size,
                              hipStream_t stream)
{
  (void)n_in; (void)out_size; (void)ws_size;
  const float* x      = (const float*)d_in[0];
  const int*   batch  = (const int*)d_in[1];
  const float* w_attn = (const float*)d_in[3];
  // d_in[4] = b_attn: softmax shift-invariant, unused
  const float* Wq     = (const float*)d_in[5];
  const float* bq     = (const float*)d_in[6];
  const float* Wk     = (const float*)d_in[7];
  const float* bk     = (const float*)d_in[8];
  const float* W1     = (const float*)d_in[9];
  const float* b1     = (const float*)d_in[10];
  const float* W2     = (const float*)d_in[11];
  const float* b2     = (const float*)d_in[12];
  float* out = (float*)d_out;
  const int N = in_sizes[0] / DD;

  float* ws = (float*)d_ws;
  float* M    = ws;                         // 256x256 f32
  float* bqk  = ws + 65536;                 // 256
  int*   offs = (int*)(ws + 65536 + 256);   // 2049 ints (pad to 2304 floats)
  float* base = ws + 65536 + 256 + 2304;
  unsigned short* u_b    = (unsigned short*)base;            // 2048*256 bf16
  unsigned short* comb_b = u_b + (size_t)GG * DD;            // 2048*1280
  unsigned short* h1_b   = comb_b + (size_t)GG * 1280;       // 2048*512
  unsigned short* Wq_b   = h1_b + (size_t)GG * 512;          // 65536
  unsigned short* Wk_b   = Wq_b + 65536;                     // 65536
  unsigned short* WkT_b  = Wk_b + 65536;                     // 65536
  unsigned short* W1T_b  = WkT_b + 65536;                    // 655360
  unsigned short* W2T_b  = W1T_b + 655360;                   // 131072

  k_prep<<<(983040 + 255) / 256, 256, 0, stream>>>(Wq, Wk, W1, W2, Wq_b, Wk_b, WkT_b, W1T_b, W2T_b);
  k_bqk<<<256, 64, 0, stream>>>(bq, Wk, bqk);
  k_offsets<<<(N + 255) / 256, 256, 0, stream>>>(batch, offs, N);
  // M = Wq @ Wk^T  (256x256, K=256), f32
  gemm_mfma<0,0><<<dim3(4, 4), 256, 0, stream>>>(Wq_b, Wk_b, nullptr, M, 256, 256, 1.0f);
  // fused per-graph pooling (writes comb cols 0..1023 and u)
  k_fused<<<GG, 256, 0, stream>>>(x, offs, w_attn, M, bqk, u_b, comb_b);
  // h_s2s = u @ Wk + bk -> comb cols [1024,1280), bf16
  gemm_mfma<0,1><<<dim3(4, 32), 256, 0, stream>>>(u_b, WkT_b, bk, comb_b + 4 * DD, 256, 1280, 1.0f);
  // h1 = gelu(comb @ W1 + b1), bf16
  gemm_mfma<1,1><<<dim3(8, 32), 256, 0, stream>>>(comb_b, W1T_b, b1, h1_b, 1280, 512, 1.0f);
  // out = h1 @ W2 + b2, f32
  gemm_mfma<0,0><<<dim3(4, 32), 256, 0, stream>>>(h1_b, W2T_b, b2, out, 512, 256, 1.0f);
}